// Round 1
// baseline (528.727 us; speedup 1.0000x reference)
//
#include <hip/hip_runtime.h>

#define NB   64
#define NH   8
#define NM   1024
#define NC   128     // K (i)
#define NMID 64      // N (o)
#define NT   256     // 4 waves
#define TM   32      // rows per streamed tile
#define NTILES (NM / TM)   // 32
#define RWS  136     // rwT row stride (shorts)
#define KFS  136     // kf tile row stride (shorts)
#define TGRAN (TM * NC / 4)  // 1024 float4 granules per tile

typedef __attribute__((ext_vector_type(8))) short s16x8;
typedef __attribute__((ext_vector_type(4))) short s16x4;
typedef __attribute__((ext_vector_type(4))) float f32x4;

__device__ __forceinline__ short f2bf(float x) {          // RNE float->bf16 bits
    union { float f; unsigned u; } v; v.f = x;
    unsigned r = (v.u + 0x7fffu + ((v.u >> 16) & 1u)) >> 16;
    return (short)r;
}
__device__ __forceinline__ float bf2f(short s) {
    union { unsigned u; float f; } v; v.u = ((unsigned)(unsigned short)s) << 16;
    return v.f;
}

// convert 4 float4 (one kf tile slice per thread) to bf16 hi/lo and stage to LDS
#define STAGE_KF(ST) do {                                                   \
    _Pragma("unroll")                                                       \
    for (int r_ = 0; r_ < 4; ++r_) {                                        \
        const int g_   = r_ * NT + t;                                       \
        const int row_ = g_ >> 5;                                           \
        const int gc_  = g_ & 31;                                           \
        const float a0 = (ST)[r_].x, a1 = (ST)[r_].y,                       \
                    a2 = (ST)[r_].z, a3 = (ST)[r_].w;                       \
        s16x4 h4_, l4_; short hh_;                                          \
        hh_ = f2bf(a0); h4_[0] = hh_; l4_[0] = f2bf(a0 - bf2f(hh_));        \
        hh_ = f2bf(a1); h4_[1] = hh_; l4_[1] = f2bf(a1 - bf2f(hh_));        \
        hh_ = f2bf(a2); h4_[2] = hh_; l4_[2] = f2bf(a2 - bf2f(hh_));        \
        hh_ = f2bf(a3); h4_[3] = hh_; l4_[3] = f2bf(a3 - bf2f(hh_));        \
        *(s16x4*)&kf_hi[row_ * KFS + gc_ * 4] = h4_;                        \
        *(s16x4*)&kf_lo[row_ * KFS + gc_ * 4] = l4_;                        \
    }                                                                       \
} while (0)

__global__ __launch_bounds__(NT, 2)
void scatt_kernel(const float* __restrict__ query,
                  const float* __restrict__ key_feat,
                  const int*   __restrict__ att_mask,
                  const float* __restrict__ value1,
                  const float* __restrict__ value2,
                  const float* __restrict__ w_basic,
                  const float* __restrict__ b_basic,
                  const float* __restrict__ w_last,
                  const float* __restrict__ b_last,
                  const float* __restrict__ w_last2,
                  const float* __restrict__ b_last2,
                  float* __restrict__ out)
{
    const int bh   = blockIdx.x;          // 0..511
    const int b    = bh >> 3;
    const int h    = bh & 7;
    const int t    = threadIdx.x;
    const int lane = t & 63;
    const int w    = t >> 6;              // wave 0..3
    const int oh   = w & 1;               // o-half
    const int rt   = w >> 1;              // row-half within tile
    const int ln15 = lane & 15;
    const int lq   = lane >> 4;           // 0..3
    const int mg   = t >> 5;              // v2 row group 0..7
    const int d4   = t & 31;              // v2 col granule
    const int half = lane & 32;           // shfl half-select

    // ---- LDS (~61.6 KB, 2 blocks/CU) ----
    __shared__ short rwT_hi[NMID * RWS];  // 17408 B : B^T hi, [o][i]
    __shared__ short rwT_lo[NMID * RWS];  // 17408 B
    __shared__ short kf_hi[TM * KFS];     //  8704 B : A tile hi, [m][i]
    __shared__ short kf_lo[TM * KFS];     //  8704 B
    __shared__ float maskf[NM];           //  4096 B : mask as float
    __shared__ float logp[2][TM];         //   256 B : per-tile logit partials
    __shared__ float poolp[4][32];        //   512 B
    __shared__ float pool_s[NMID];        //   256 B
    __shared__ float v2part[8][NC];       //  4096 B
    __shared__ float red[8];
    __shared__ float csum_s;

    const float*  kf  = key_feat + (size_t)bh * NM * NC;
    const float*  v2g = value2   + (size_t)bh * NM * NC;
    const float4* kf4 = (const float4*)kf;
    const float4* v24 = (const float4*)v2g;

    // ---- prefetch tile 0 of BOTH streams (32 KB/block in flight) ----
    float4 stA[4], stV[4];
    #pragma unroll
    for (int r = 0; r < 4; ++r) stA[r] = kf4[r * NT + t];
    #pragma unroll
    for (int r = 0; r < 4; ++r) stV[r] = v24[r * NT + t];

    // ---- mask -> LDS, plus unmasked count ----
    float cs = 0.f;
    #pragma unroll
    for (int m = t; m < NM; m += NT) {
        const int mv = att_mask[b * NM + m];
        maskf[m] = (float)mv;
        cs += (float)mv;
    }
    #pragma unroll
    for (int sh = 32; sh > 0; sh >>= 1) cs += __shfl_xor(cs, sh, 64);
    if (lane == 0) red[w] = cs;

    // ---- build rwT = (q (.) w_basic)^T as bf16 hi/lo ----
    {
        const float* wb = w_basic + (size_t)h * NC * NMID;
        const float* qp = query + bh * NC;
        #pragma unroll 4
        for (int r = 0; r < 32; ++r) {
            const int f = r * NT + t;      // = i*64 + o (coalesced over wb)
            const int o = f & 63;
            const int i = f >> 6;
            const float x = qp[i] * wb[f];
            const short hi = f2bf(x);
            rwT_hi[o * RWS + i] = hi;
            rwT_lo[o * RWS + i] = f2bf(x - bf2f(hi));
        }
    }
    __syncthreads();                       // rwT, maskf, red visible
    if (t == 0) csum_s = red[0] + red[1] + red[2] + red[3];

    // ---- hoist B fragments (tile-invariant) ----
    s16x8 Bh[2][4], Bl[2][4];
    #pragma unroll
    for (int otl = 0; otl < 2; ++otl) {
        const int o = oh * 32 + otl * 16 + ln15;
        #pragma unroll
        for (int ks = 0; ks < 4; ++ks) {
            const int off = o * RWS + ks * 32 + lq * 8;
            Bh[otl][ks] = *(const s16x8*)&rwT_hi[off];
            Bl[otl][ks] = *(const s16x8*)&rwT_lo[off];
        }
    }

    const int o_0 = oh * 32 + ln15;
    const int o_1 = o_0 + 16;
    const float bb0 = b_basic[h * NMID + o_0];
    const float bb1 = b_basic[h * NMID + o_1];
    const float wl0 = w_last[h * NMID + o_0];
    const float wl1 = w_last[h * NMID + o_1];
    const float bl  = b_last[h];

    float pool0 = 0.f, pool1 = 0.f;
    f32x4 accd = {0.f, 0.f, 0.f, 0.f};    // online-rescaled v2 accumulator
    float mx_run = -1e30f;                 // running max (identical in all threads)
    float s_run  = 0.f;                    // running softmax denom
    const int abase = (rt * 16 + ln15) * KFS + lq * 8;

    // stage tile 0, issue kf tile 1
    STAGE_KF(stA);
    #pragma unroll
    for (int r = 0; r < 4; ++r) stA[r] = kf4[TGRAN + r * NT + t];
    __syncthreads();                       // kf tile0 visible

    // ---- fused streaming loop: kf MFMA + online softmax + v2 accumulate ----
    #pragma unroll 1
    for (int tile = 0; tile < NTILES; ++tile) {
        f32x4 acc0 = {0.f, 0.f, 0.f, 0.f};
        f32x4 acc1 = {0.f, 0.f, 0.f, 0.f};
        #pragma unroll
        for (int ks = 0; ks < 4; ++ks) {
            const s16x8 Ah = *(const s16x8*)&kf_hi[abase + ks * 32];
            const s16x8 Al = *(const s16x8*)&kf_lo[abase + ks * 32];
            acc0 = __builtin_amdgcn_mfma_f32_16x16x32_bf16(Ah, Bh[0][ks], acc0, 0, 0, 0);
            acc1 = __builtin_amdgcn_mfma_f32_16x16x32_bf16(Ah, Bh[1][ks], acc1, 0, 0, 0);
            acc0 = __builtin_amdgcn_mfma_f32_16x16x32_bf16(Al, Bh[0][ks], acc0, 0, 0, 0);
            acc1 = __builtin_amdgcn_mfma_f32_16x16x32_bf16(Al, Bh[1][ks], acc1, 0, 0, 0);
            acc0 = __builtin_amdgcn_mfma_f32_16x16x32_bf16(Ah, Bl[0][ks], acc0, 0, 0, 0);
            acc1 = __builtin_amdgcn_mfma_f32_16x16x32_bf16(Ah, Bl[1][ks], acc1, 0, 0, 0);
        }

        // epilogue: relu + pool + logit partials. D layout: col=lane&15, row=(lane>>4)*4+reg
        const int rbase = rt * 16 + lq * 4;
        float c4[4];
        #pragma unroll
        for (int reg = 0; reg < 4; ++reg) {
            const float mvf = maskf[tile * TM + rbase + reg];
            const float y0 = fmaxf(acc0[reg] + bb0, 0.f);
            const float y1 = fmaxf(acc1[reg] + bb1, 0.f);
            pool0 = fmaf(mvf, y0, pool0);
            pool1 = fmaf(mvf, y1, pool1);
            c4[reg] = fmaf(y0, wl0, y1 * wl1);
        }
        #pragma unroll
        for (int reg = 0; reg < 4; ++reg) {
            #pragma unroll
            for (int sh = 1; sh < 16; sh <<= 1) c4[reg] += __shfl_xor(c4[reg], sh, 64);
        }
        if (ln15 == 0) {
            #pragma unroll
            for (int reg = 0; reg < 4; ++reg) logp[oh][rbase + reg] = c4[reg];
        }
        __syncthreads();   // B1: logit partials visible; all kf ds_reads done

        // online softmax combine — EVERY wave computes it redundantly in registers
        // (identical arithmetic => bit-identical mx_run/s_run in all threads)
        const int lrow = lane & 31;                    // tile row this lane owns
        float lg = logp[0][lrow] + logp[1][lrow] + bl;
        lg = (maskf[tile * TM + lrow] != 0.f) ? lg : -1e9f;
        float tmax = lg;
        #pragma unroll
        for (int sh = 1; sh <= 16; sh <<= 1) tmax = fmaxf(tmax, __shfl_xor(tmax, sh, 64));
        const float nmx = fmaxf(mx_run, tmax);
        const float fre = __expf(mx_run - nmx);        // rescale factor (==1 when no new max)
        const float e   = __expf(lg - nmx);            // this lane's row weight
        float es = e;
        #pragma unroll
        for (int sh = 1; sh <= 16; sh <<= 1) es += __shfl_xor(es, sh, 64);
        s_run = s_run * fre + es;
        mx_run = nmx;

        // gather e for this thread's 4 v2 rows (rows mg+8k) via broadcast shfl
        float ek[4];
        #pragma unroll
        for (int k = 0; k < 4; ++k) ek[k] = __shfl(e, half + mg + 8 * k, 64);

        // v2 accumulate from registers (value2 tile prefetched last iter)
        accd = accd * fre;
        #pragma unroll
        for (int k = 0; k < 4; ++k) {
            accd[0] = fmaf(ek[k], stV[k].x, accd[0]);
            accd[1] = fmaf(ek[k], stV[k].y, accd[1]);
            accd[2] = fmaf(ek[k], stV[k].z, accd[2]);
            accd[3] = fmaf(ek[k], stV[k].w, accd[3]);
        }
        // issue next value2 tile immediately after consumption
        if (tile + 1 < NTILES) {
            #pragma unroll
            for (int r = 0; r < 4; ++r)
                stV[r] = v24[(size_t)(tile + 1) * TGRAN + r * NT + t];
        }

        // stage next kf tile (safe: all ds_reads of current tile done before B1)
        if (tile + 1 < NTILES) STAGE_KF(stA);
        __syncthreads();   // B2: staged tile + logp-reuse protection
        if (tile + 2 < NTILES) {
            #pragma unroll
            for (int r = 0; r < 4; ++r)
                stA[r] = kf4[(size_t)(tile + 2) * TGRAN + r * NT + t];
        }
    }

    // ---- final reductions ----
    pool0 += __shfl_xor(pool0, 16, 64); pool0 += __shfl_xor(pool0, 32, 64);
    pool1 += __shfl_xor(pool1, 16, 64); pool1 += __shfl_xor(pool1, 32, 64);
    if (lane < 16) { poolp[w][lane] = pool0; poolp[w][16 + lane] = pool1; }
    ((float4*)&v2part[mg][0])[d4] = make_float4(accd[0], accd[1], accd[2], accd[3]);
    __syncthreads();   // F1

    if (t < NMID) {
        const int ohp = t >> 5, j = t & 31;
        pool_s[t] = (poolp[ohp][j] + poolp[ohp + 2][j]) / csum_s;
    }
    __syncthreads();   // F2

    // ---- channel gate + output ----
    if (t < NC) {
        float v2d = 0.f;
        #pragma unroll
        for (int g = 0; g < 8; ++g) v2d += v2part[g][t];
        v2d /= s_run;                       // softmax denom (in registers, all threads)
        float accg = b_last2[h * NC + t];
        const float* wl2 = w_last2 + (size_t)h * NMID * NC + t;
        #pragma unroll 8
        for (int o = 0; o < NMID; ++o)
            accg = fmaf(pool_s[o], wl2[(size_t)o * NC], accg);
        const float ach = 1.f / (1.f + __expf(-accg));
        out[bh * NC + t] = value1[bh * NC + t] * v2d * ach;
    }
}

extern "C" void kernel_launch(void* const* d_in, const int* in_sizes, int n_in,
                              void* d_out, int out_size, void* d_ws, size_t ws_size,
                              hipStream_t stream) {
    (void)in_sizes; (void)n_in; (void)out_size; (void)d_ws; (void)ws_size;
    const float* query    = (const float*)d_in[0];
    const float* key_feat = (const float*)d_in[1];
    const int*   att_mask = (const int*)d_in[2];
    const float* value1   = (const float*)d_in[3];
    const float* value2   = (const float*)d_in[4];
    const float* w_basic  = (const float*)d_in[5];
    const float* b_basic  = (const float*)d_in[6];
    const float* w_last   = (const float*)d_in[7];
    const float* b_last   = (const float*)d_in[8];
    const float* w_last2  = (const float*)d_in[9];
    const float* b_last2  = (const float*)d_in[10];
    float* outp = (float*)d_out;

    scatt_kernel<<<dim3(NB * NH), dim3(NT), 0, stream>>>(
        query, key_feat, att_mask, value1, value2,
        w_basic, b_basic, w_last, b_last, w_last2, b_last2, outp);
}